// Round 5
// baseline (214.858 us; speedup 1.0000x reference)
//
#include <hip/hip_runtime.h>

#define TPB 256
constexpr int B_ = 8, C_ = 192, H_ = 56, W_ = 56, O_ = 384;
constexpr int HW_ = H_ * W_;          // 3136
constexpr int NOFF = 18;              // 9 taps * 2 (dy,dx)
constexpr int NPIX = B_ * HW_;        // 25088 = 196 * 128

typedef __attribute__((ext_vector_type(8))) short short8v;
typedef __attribute__((ext_vector_type(4))) float f32x4;

__device__ inline unsigned short f2bf(float f) {
  unsigned u = __builtin_bit_cast(unsigned, f);
  unsigned r = (u + 0x7fffu + ((u >> 16) & 1u)) >> 16;
  return (unsigned short)r;
}
__device__ inline float bflo(unsigned u) {
  return __builtin_bit_cast(float, u << 16);
}
__device__ inline float bfhi(unsigned u) {
  return __builtin_bit_cast(float, u & 0xffff0000u);
}

// ---------------- K0: pw_w (O,C) fp32 -> bf16 same layout ----------------
__global__ __launch_bounds__(TPB) void k_wb(const float* __restrict__ pw,
                                            unsigned short* __restrict__ wtb) {
  int i = blockIdx.x * TPB + threadIdx.x;
  if (i < O_ * C_) wtb[i] = f2bf(pw[i]);
}

// ------- K1+XT fused: depthwise 3x3 -> t1 (fp32) AND x -> x_t bf16 -------
// block = 64 pixels x 192 channels of one batch; LDS transpose for x_t.
__global__ __launch_bounds__(TPB) void k_dwxt(const float* __restrict__ x,
                                              const float* __restrict__ wdw,
                                              float* __restrict__ t1,
                                              unsigned short* __restrict__ xt) {
  __shared__ unsigned short tile[64 * 198];
  int tid = threadIdx.x;
  int P0 = blockIdx.x * 64;
  int b = blockIdx.y;
#pragma unroll
  for (int i = 0; i < 48; ++i) {
    int idx = i * TPB + tid;
    int px = idx & 63;
    int c = idx >> 6;
    int p = P0 + px;
    int h = p / W_;
    int w = p - h * W_;
    size_t base = ((size_t)(b * C_ + c)) * HW_ + p;
    float xc = x[base];
    const float* wp = wdw + c * 9;
    float acc = 0.f;
#pragma unroll
    for (int di = 0; di < 3; ++di) {
      int hh = h + di - 1;
      if ((unsigned)hh >= (unsigned)H_) continue;
#pragma unroll
      for (int dj = 0; dj < 3; ++dj) {
        int ww = w + dj - 1;
        if ((unsigned)ww >= (unsigned)W_) continue;
        float xv = (di == 1 && dj == 1) ? xc : x[base + (di - 1) * W_ + (dj - 1)];
        acc += xv * wp[di * 3 + dj];
      }
    }
    t1[base] = acc;
    tile[px * 198 + c] = f2bf(xc);
  }
  __syncthreads();
  unsigned* xtu = (unsigned*)xt;
#pragma unroll
  for (int i = 0; i < 24; ++i) {
    int d = i * TPB + tid;            // dword index in 64*96
    int px = d / 96;
    int c2 = d - px * 96;
    unsigned v = *(const unsigned*)&tile[px * 198 + c2 * 2];
    xtu[((size_t)b * HW_ + P0 + px) * 96 + c2] = v;
  }
}

// ---------------- K2: pointwise C->18 + clip ----------------
__global__ __launch_bounds__(TPB) void k_pw18(const float* __restrict__ t1,
                                              const float* __restrict__ wpw,
                                              float* __restrict__ offp) {
  int idx = blockIdx.x * TPB + threadIdx.x;
  int q = idx % (HW_ / 4);
  int ch = (idx / (HW_ / 4)) % NOFF;
  int b = idx / (NOFF * (HW_ / 4));
  const float4* tp = (const float4*)(t1 + (size_t)b * C_ * HW_) + q;
  const float* wp = wpw + ch * C_;
  float4 acc = make_float4(0.f, 0.f, 0.f, 0.f);
  for (int c = 0; c < C_; ++c) {
    float4 v = tp[c * (HW_ / 4)];
    float wv = wp[c];
    acc.x += v.x * wv; acc.y += v.y * wv;
    acc.z += v.z * wv; acc.w += v.w * wv;
  }
  float4 r;
  r.x = fminf(fmaxf(acc.x, -1.f), 1.f);
  r.y = fminf(fmaxf(acc.y, -1.f), 1.f);
  r.z = fminf(fmaxf(acc.z, -1.f), 1.f);
  r.w = fminf(fmaxf(acc.w, -1.f), 1.f);
  float4* op = (float4*)(offp + ((size_t)b * NOFF + ch) * HW_) + q;
  *op = r;
}

// ------- K3: deform sample + dcn; 8 lanes/px, 24ch/lane, uint4 gathers ----
__global__ __launch_bounds__(TPB) void k_deform4(const unsigned short* __restrict__ xt,
                                                 const float* __restrict__ offp,
                                                 const float* __restrict__ dcn,
                                                 unsigned short* __restrict__ y1t) {
  __shared__ __align__(16) float dcnT[9 * C_];
  int tid = threadIdx.x;
  for (int t = tid; t < 9 * C_; t += TPB) {
    int k = t / C_, c = t - k * C_;
    dcnT[t] = dcn[c * 9 + k];
  }
  __syncthreads();

  int px = blockIdx.x * 32 + (tid >> 3);
  int sub = tid & 7;
  int cb = sub * 24;                  // 8 lanes x 24 ch = 192
  int b = px / HW_;
  int hw = px - b * HW_;
  int h = hw / W_;
  int w = hw - h * W_;
  const float* op = offp + (size_t)b * NOFF * HW_ + hw;
  float dyr[9], dxr[9];
#pragma unroll
  for (int k = 0; k < 9; ++k) {
    dyr[k] = op[(2 * k) * HW_];
    dxr[k] = op[(2 * k + 1) * HW_];
  }

  float acc[24];
#pragma unroll
  for (int j = 0; j < 24; ++j) acc[j] = 0.f;
  int pb = b * HW_;

#pragma unroll
  for (int k = 0; k < 9; ++k) {
    const int ky = k / 3 - 1;
    const int kx = k - (k / 3) * 3 - 1;
    float ys = (float)(h + ky) + dyr[k];
    float xs = (float)(w + kx) + dxr[k];
    float y0f = floorf(ys), x0f = floorf(xs);
    float ty = ys - y0f, tx = xs - x0f;
    int y0 = (int)y0f, x0 = (int)x0f;
    int y1 = y0 + 1, x1 = x0 + 1;
    float fy0 = ((unsigned)y0 < (unsigned)H_) ? 1.f : 0.f;
    float fy1 = ((unsigned)y1 < (unsigned)H_) ? 1.f : 0.f;
    float fx0 = ((unsigned)x0 < (unsigned)W_) ? 1.f : 0.f;
    float fx1 = ((unsigned)x1 < (unsigned)W_) ? 1.f : 0.f;
    int y0c = y0 < 0 ? 0 : (y0 > H_ - 1 ? H_ - 1 : y0);
    int y1c = y1 < 0 ? 0 : (y1 > H_ - 1 ? H_ - 1 : y1);
    int x0c = x0 < 0 ? 0 : (x0 > W_ - 1 ? W_ - 1 : x0);
    int x1c = x1 < 0 ? 0 : (x1 > W_ - 1 ? W_ - 1 : x1);
    float omty = 1.f - ty, omtx = 1.f - tx;
    float w00 = omty * omtx * fy0 * fx0;
    float w01 = omty * tx * fy0 * fx1;
    float w10 = ty * omtx * fy1 * fx0;
    float w11 = ty * tx * fy1 * fx1;
    int r0 = (pb + y0c * W_) * C_;
    int r1 = (pb + y1c * W_) * C_;
    int p00 = r0 + x0c * C_ + cb;
    int p01 = r0 + x1c * C_ + cb;
    int p10 = r1 + x0c * C_ + cb;
    int p11 = r1 + x1c * C_ + cb;

    uint4 dA[3], dB[3], dC[3], dD[3];
#pragma unroll
    for (int r = 0; r < 3; ++r) {
      dA[r] = *(const uint4*)(xt + p00 + r * 8);
      dB[r] = *(const uint4*)(xt + p01 + r * 8);
      dC[r] = *(const uint4*)(xt + p10 + r * 8);
      dD[r] = *(const uint4*)(xt + p11 + r * 8);
    }
#pragma unroll
    for (int r = 0; r < 3; ++r) {
      const float* dwp = &dcnT[k * C_ + cb + r * 8];
      f32x4 dw0 = *(const f32x4*)dwp;
      f32x4 dw1 = *(const f32x4*)(dwp + 4);
      float s;
      s = w00 * bflo(dA[r].x) + w01 * bflo(dB[r].x) + w10 * bflo(dC[r].x) + w11 * bflo(dD[r].x);
      acc[r * 8 + 0] += s * dw0.x;
      s = w00 * bfhi(dA[r].x) + w01 * bfhi(dB[r].x) + w10 * bfhi(dC[r].x) + w11 * bfhi(dD[r].x);
      acc[r * 8 + 1] += s * dw0.y;
      s = w00 * bflo(dA[r].y) + w01 * bflo(dB[r].y) + w10 * bflo(dC[r].y) + w11 * bflo(dD[r].y);
      acc[r * 8 + 2] += s * dw0.z;
      s = w00 * bfhi(dA[r].y) + w01 * bfhi(dB[r].y) + w10 * bfhi(dC[r].y) + w11 * bfhi(dD[r].y);
      acc[r * 8 + 3] += s * dw0.w;
      s = w00 * bflo(dA[r].z) + w01 * bflo(dB[r].z) + w10 * bflo(dC[r].z) + w11 * bflo(dD[r].z);
      acc[r * 8 + 4] += s * dw1.x;
      s = w00 * bfhi(dA[r].z) + w01 * bfhi(dB[r].z) + w10 * bfhi(dC[r].z) + w11 * bfhi(dD[r].z);
      acc[r * 8 + 5] += s * dw1.y;
      s = w00 * bflo(dA[r].w) + w01 * bflo(dB[r].w) + w10 * bflo(dC[r].w) + w11 * bflo(dD[r].w);
      acc[r * 8 + 6] += s * dw1.z;
      s = w00 * bfhi(dA[r].w) + w01 * bfhi(dB[r].w) + w10 * bfhi(dC[r].w) + w11 * bfhi(dD[r].w);
      acc[r * 8 + 7] += s * dw1.w;
    }
  }

  int ob = px * C_ + cb;
#pragma unroll
  for (int r = 0; r < 3; ++r) {
    uint4 pk;
    pk.x = (unsigned)f2bf(acc[r * 8 + 0]) | ((unsigned)f2bf(acc[r * 8 + 1]) << 16);
    pk.y = (unsigned)f2bf(acc[r * 8 + 2]) | ((unsigned)f2bf(acc[r * 8 + 3]) << 16);
    pk.z = (unsigned)f2bf(acc[r * 8 + 4]) | ((unsigned)f2bf(acc[r * 8 + 5]) << 16);
    pk.w = (unsigned)f2bf(acc[r * 8 + 6]) | ((unsigned)f2bf(acc[r * 8 + 7]) << 16);
    *(uint4*)(y1t + ob + r * 8) = pk;
  }
}

// ---------------- K4: MFMA bf16 GEMM with LDS-staged, swizzled B-tile -----
__global__ __launch_bounds__(TPB) void k_gemm2(const unsigned short* __restrict__ y1t,
                                               const unsigned short* __restrict__ wtb,
                                               float* __restrict__ out) {
  __shared__ __align__(16) unsigned short bsm[128 * 192];  // 48 KB
  int tid = threadIdx.x;
  int n0 = blockIdx.x * 128;
  int m0 = blockIdx.y * 64;

  const char* gsrc = (const char*)(y1t + (size_t)n0 * C_);
  char* sbase = (char*)bsm;
#pragma unroll
  for (int r = 0; r < 12; ++r) {
    int L = (r * TPB + tid) * 16;
    int row = L / 384;
    int cb = L - row * 384;
    uint4 v = *(const uint4*)(gsrc + row * 384 + cb);
    *(uint4*)(sbase + (row * 384 + (cb ^ ((row & 7) << 4)))) = v;
  }
  __syncthreads();

  int wid = tid >> 6;
  int lane = tid & 63;
  int col = lane & 15;
  int kg = lane >> 4;

  f32x4 acc[4][2];
#pragma unroll
  for (int mf = 0; mf < 4; ++mf)
#pragma unroll
    for (int nf = 0; nf < 2; ++nf) acc[mf][nf] = (f32x4){0.f, 0.f, 0.f, 0.f};

#pragma unroll
  for (int k0 = 0; k0 < C_; k0 += 32) {
    short8v a[4], bfr[2];
#pragma unroll
    for (int mf = 0; mf < 4; ++mf)
      a[mf] = *(const short8v*)(wtb + (m0 + mf * 16 + col) * C_ + k0 + kg * 8);
#pragma unroll
    for (int nf = 0; nf < 2; ++nf) {
      int brow = wid * 32 + nf * 16 + col;
      int kb = (k0 + kg * 8) * 2;
      bfr[nf] = *(const short8v*)(sbase + brow * 384 + (kb ^ ((brow & 7) << 4)));
    }
#pragma unroll
    for (int mf = 0; mf < 4; ++mf)
#pragma unroll
      for (int nf = 0; nf < 2; ++nf)
        acc[mf][nf] = __builtin_amdgcn_mfma_f32_16x16x32_bf16(a[mf], bfr[nf], acc[mf][nf], 0, 0, 0);
  }

#pragma unroll
  for (int mf = 0; mf < 4; ++mf) {
#pragma unroll
    for (int nf = 0; nf < 2; ++nf) {
      int p = n0 + wid * 32 + nf * 16 + col;
      int bb = p / HW_;
      int hw = p - bb * HW_;
#pragma unroll
      for (int reg = 0; reg < 4; ++reg) {
        int o = m0 + mf * 16 + kg * 4 + reg;
        float a = acc[mf][nf][reg];
        float r = a * fminf(fmaxf(a + 3.f, 0.f), 6.f) * (1.f / 6.f);
        out[((size_t)bb * O_ + o) * HW_ + hw] = r;
      }
    }
  }
}

extern "C" void kernel_launch(void* const* d_in, const int* in_sizes, int n_in,
                              void* d_out, int out_size, void* d_ws, size_t ws_size,
                              hipStream_t stream) {
  const float* x = (const float*)d_in[0];
  const float* og_dw = (const float*)d_in[1];
  const float* og_pw = (const float*)d_in[2];
  const float* dcn_w = (const float*)d_in[3];
  const float* pw_w = (const float*)d_in[4];
  float* out = (float*)d_out;

  float* ws = (float*)d_ws;
  float* t1 = ws;                                        // B*C*HW fp32
  float* offp = t1 + (size_t)B_ * C_ * HW_;              // B*18*HW fp32
  unsigned short* y1t = (unsigned short*)(offp + (size_t)B_ * NOFF * HW_);
  unsigned short* wtb = y1t + (size_t)NPIX * C_;
  unsigned short* x_t = wtb + (size_t)O_ * C_;

  k_wb<<<(O_ * C_ + TPB - 1) / TPB, TPB, 0, stream>>>(pw_w, wtb);
  k_dwxt<<<dim3(HW_ / 64, B_), TPB, 0, stream>>>(x, og_dw, t1, x_t);
  k_pw18<<<(B_ * NOFF * (HW_ / 4)) / TPB, TPB, 0, stream>>>(t1, og_pw, offp);
  k_deform4<<<NPIX / 32, TPB, 0, stream>>>(x_t, offp, dcn_w, y1t);
  k_gemm2<<<dim3(NPIX / 128, O_ / 64), TPB, 0, stream>>>(y1t, wtb, out);
}

// Round 6
// 145.569 us; speedup vs baseline: 1.4760x; 1.4760x over previous
//
#include <hip/hip_runtime.h>

#define TPB 256
constexpr int B_ = 8, C_ = 192, H_ = 56, W_ = 56, O_ = 384;
constexpr int HW_ = H_ * W_;          // 3136
constexpr int NOFF = 18;              // 9 taps * 2 (dy,dx)
constexpr int NPIX = B_ * HW_;        // 25088 = 196 * 128

typedef __attribute__((ext_vector_type(8))) short short8v;
typedef __attribute__((ext_vector_type(4))) float f32x4;

__device__ inline unsigned short f2bf(float f) {
  unsigned u = __builtin_bit_cast(unsigned, f);
  unsigned r = (u + 0x7fffu + ((u >> 16) & 1u)) >> 16;
  return (unsigned short)r;
}
__device__ inline float bflo(unsigned u) {
  return __builtin_bit_cast(float, u << 16);
}
__device__ inline float bfhi(unsigned u) {
  return __builtin_bit_cast(float, u & 0xffff0000u);
}

// ---------------- K0: pw_w (O,C) fp32 -> bf16 same layout ----------------
__global__ __launch_bounds__(TPB) void k_wb(const float* __restrict__ pw,
                                            unsigned short* __restrict__ wtb) {
  int i = blockIdx.x * TPB + threadIdx.x;
  if (i < O_ * C_) wtb[i] = f2bf(pw[i]);
}

// ---------------- K1: depthwise 3x3, pad 1 (elementwise, full grid) -------
__global__ __launch_bounds__(TPB) void k_dw(const float* __restrict__ x,
                                            const float* __restrict__ wdw,
                                            float* __restrict__ t1) {
  int idx = blockIdx.x * TPB + threadIdx.x;
  if (idx >= B_ * C_ * HW_) return;
  int w = idx % W_;
  int h = (idx / W_) % H_;
  int c = (idx / HW_) % C_;
  const float* wp = wdw + c * 9;
  float acc = 0.f;
#pragma unroll
  for (int i = 0; i < 3; ++i) {
    int hh = h + i - 1;
    if ((unsigned)hh >= (unsigned)H_) continue;
#pragma unroll
    for (int j = 0; j < 3; ++j) {
      int ww = w + j - 1;
      if ((unsigned)ww >= (unsigned)W_) continue;
      acc += x[idx + (i - 1) * W_ + (j - 1)] * wp[i * 3 + j];
    }
  }
  t1[idx] = acc;
}

// ---------------- K2: pointwise C->18 + clip ----------------
__global__ __launch_bounds__(TPB) void k_pw18(const float* __restrict__ t1,
                                              const float* __restrict__ wpw,
                                              float* __restrict__ offp) {
  int idx = blockIdx.x * TPB + threadIdx.x;
  int q = idx % (HW_ / 4);
  int ch = (idx / (HW_ / 4)) % NOFF;
  int b = idx / (NOFF * (HW_ / 4));
  const float4* tp = (const float4*)(t1 + (size_t)b * C_ * HW_) + q;
  const float* wp = wpw + ch * C_;
  float4 acc = make_float4(0.f, 0.f, 0.f, 0.f);
  for (int c = 0; c < C_; ++c) {
    float4 v = tp[c * (HW_ / 4)];
    float wv = wp[c];
    acc.x += v.x * wv; acc.y += v.y * wv;
    acc.z += v.z * wv; acc.w += v.w * wv;
  }
  float4 r;
  r.x = fminf(fmaxf(acc.x, -1.f), 1.f);
  r.y = fminf(fmaxf(acc.y, -1.f), 1.f);
  r.z = fminf(fmaxf(acc.z, -1.f), 1.f);
  r.w = fminf(fmaxf(acc.w, -1.f), 1.f);
  float4* op = (float4*)(offp + ((size_t)b * NOFF + ch) * HW_) + q;
  *op = r;
}

// ---------------- K_XT: x[b][c][h][w] fp32 -> x_t[b][hw][c] bf16 ----------
__global__ __launch_bounds__(TPB) void k_xt(const float* __restrict__ x,
                                            unsigned short* __restrict__ xt) {
  __shared__ unsigned short tile[64 * 198];
  int tid = threadIdx.x;
  int P0 = blockIdx.x * 64;
  int b = blockIdx.y;
#pragma unroll
  for (int i = 0; i < 48; ++i) {
    int idx = i * TPB + tid;
    int px = idx & 63;
    int c = idx >> 6;
    float v = x[((size_t)(b * C_ + c)) * HW_ + P0 + px];
    tile[px * 198 + c] = f2bf(v);
  }
  __syncthreads();
  unsigned* xtu = (unsigned*)xt;
#pragma unroll
  for (int i = 0; i < 24; ++i) {
    int d = i * TPB + tid;            // dword index in 64*96
    int px = d / 96;
    int c2 = d - px * 96;
    unsigned v = *(const unsigned*)&tile[px * 198 + c2 * 2];
    xtu[((size_t)b * HW_ + P0 + px) * 96 + c2] = v;
  }
}

// ------- K3: deform sample + dcn; 8 lanes/px, 24ch/lane, uint4 gathers ----
__global__ __launch_bounds__(TPB) void k_deform4(const unsigned short* __restrict__ xt,
                                                 const float* __restrict__ offp,
                                                 const float* __restrict__ dcn,
                                                 unsigned short* __restrict__ y1t) {
  __shared__ __align__(16) float dcnT[9 * C_];
  int tid = threadIdx.x;
  for (int t = tid; t < 9 * C_; t += TPB) {
    int k = t / C_, c = t - k * C_;
    dcnT[t] = dcn[c * 9 + k];
  }
  __syncthreads();

  int px = blockIdx.x * 32 + (tid >> 3);
  int sub = tid & 7;
  int cb = sub * 24;                  // 8 lanes x 24 ch = 192
  int b = px / HW_;
  int hw = px - b * HW_;
  int h = hw / W_;
  int w = hw - h * W_;
  const float* op = offp + (size_t)b * NOFF * HW_ + hw;
  float dyr[9], dxr[9];
#pragma unroll
  for (int k = 0; k < 9; ++k) {
    dyr[k] = op[(2 * k) * HW_];
    dxr[k] = op[(2 * k + 1) * HW_];
  }

  float acc[24];
#pragma unroll
  for (int j = 0; j < 24; ++j) acc[j] = 0.f;
  int pb = b * HW_;

#pragma unroll
  for (int k = 0; k < 9; ++k) {
    const int ky = k / 3 - 1;
    const int kx = k - (k / 3) * 3 - 1;
    float ys = (float)(h + ky) + dyr[k];
    float xs = (float)(w + kx) + dxr[k];
    float y0f = floorf(ys), x0f = floorf(xs);
    float ty = ys - y0f, tx = xs - x0f;
    int y0 = (int)y0f, x0 = (int)x0f;
    int y1 = y0 + 1, x1 = x0 + 1;
    float fy0 = ((unsigned)y0 < (unsigned)H_) ? 1.f : 0.f;
    float fy1 = ((unsigned)y1 < (unsigned)H_) ? 1.f : 0.f;
    float fx0 = ((unsigned)x0 < (unsigned)W_) ? 1.f : 0.f;
    float fx1 = ((unsigned)x1 < (unsigned)W_) ? 1.f : 0.f;
    int y0c = y0 < 0 ? 0 : (y0 > H_ - 1 ? H_ - 1 : y0);
    int y1c = y1 < 0 ? 0 : (y1 > H_ - 1 ? H_ - 1 : y1);
    int x0c = x0 < 0 ? 0 : (x0 > W_ - 1 ? W_ - 1 : x0);
    int x1c = x1 < 0 ? 0 : (x1 > W_ - 1 ? W_ - 1 : x1);
    float omty = 1.f - ty, omtx = 1.f - tx;
    float w00 = omty * omtx * fy0 * fx0;
    float w01 = omty * tx * fy0 * fx1;
    float w10 = ty * omtx * fy1 * fx0;
    float w11 = ty * tx * fy1 * fx1;
    int r0 = (pb + y0c * W_) * C_;
    int r1 = (pb + y1c * W_) * C_;
    int p00 = r0 + x0c * C_ + cb;
    int p01 = r0 + x1c * C_ + cb;
    int p10 = r1 + x0c * C_ + cb;
    int p11 = r1 + x1c * C_ + cb;

    uint4 dA[3], dB[3], dC[3], dD[3];
#pragma unroll
    for (int r = 0; r < 3; ++r) {
      dA[r] = *(const uint4*)(xt + p00 + r * 8);
      dB[r] = *(const uint4*)(xt + p01 + r * 8);
      dC[r] = *(const uint4*)(xt + p10 + r * 8);
      dD[r] = *(const uint4*)(xt + p11 + r * 8);
    }
#pragma unroll
    for (int r = 0; r < 3; ++r) {
      const float* dwp = &dcnT[k * C_ + cb + r * 8];
      f32x4 dw0 = *(const f32x4*)dwp;
      f32x4 dw1 = *(const f32x4*)(dwp + 4);
      float s;
      s = w00 * bflo(dA[r].x) + w01 * bflo(dB[r].x) + w10 * bflo(dC[r].x) + w11 * bflo(dD[r].x);
      acc[r * 8 + 0] += s * dw0.x;
      s = w00 * bfhi(dA[r].x) + w01 * bfhi(dB[r].x) + w10 * bfhi(dC[r].x) + w11 * bfhi(dD[r].x);
      acc[r * 8 + 1] += s * dw0.y;
      s = w00 * bflo(dA[r].y) + w01 * bflo(dB[r].y) + w10 * bflo(dC[r].y) + w11 * bflo(dD[r].y);
      acc[r * 8 + 2] += s * dw0.z;
      s = w00 * bfhi(dA[r].y) + w01 * bfhi(dB[r].y) + w10 * bfhi(dC[r].y) + w11 * bfhi(dD[r].y);
      acc[r * 8 + 3] += s * dw0.w;
      s = w00 * bflo(dA[r].z) + w01 * bflo(dB[r].z) + w10 * bflo(dC[r].z) + w11 * bflo(dD[r].z);
      acc[r * 8 + 4] += s * dw1.x;
      s = w00 * bfhi(dA[r].z) + w01 * bfhi(dB[r].z) + w10 * bfhi(dC[r].z) + w11 * bfhi(dD[r].z);
      acc[r * 8 + 5] += s * dw1.y;
      s = w00 * bflo(dA[r].w) + w01 * bflo(dB[r].w) + w10 * bflo(dC[r].w) + w11 * bflo(dD[r].w);
      acc[r * 8 + 6] += s * dw1.z;
      s = w00 * bfhi(dA[r].w) + w01 * bfhi(dB[r].w) + w10 * bfhi(dC[r].w) + w11 * bfhi(dD[r].w);
      acc[r * 8 + 7] += s * dw1.w;
    }
  }

  int ob = px * C_ + cb;
#pragma unroll
  for (int r = 0; r < 3; ++r) {
    uint4 pk;
    pk.x = (unsigned)f2bf(acc[r * 8 + 0]) | ((unsigned)f2bf(acc[r * 8 + 1]) << 16);
    pk.y = (unsigned)f2bf(acc[r * 8 + 2]) | ((unsigned)f2bf(acc[r * 8 + 3]) << 16);
    pk.z = (unsigned)f2bf(acc[r * 8 + 4]) | ((unsigned)f2bf(acc[r * 8 + 5]) << 16);
    pk.w = (unsigned)f2bf(acc[r * 8 + 6]) | ((unsigned)f2bf(acc[r * 8 + 7]) << 16);
    *(uint4*)(y1t + ob + r * 8) = pk;
  }
}

// ---------------- K4: MFMA bf16 GEMM with LDS-staged, swizzled B-tile -----
__global__ __launch_bounds__(TPB) void k_gemm2(const unsigned short* __restrict__ y1t,
                                               const unsigned short* __restrict__ wtb,
                                               float* __restrict__ out) {
  __shared__ __align__(16) unsigned short bsm[128 * 192];  // 48 KB
  int tid = threadIdx.x;
  int n0 = blockIdx.x * 128;
  int m0 = blockIdx.y * 64;

  const char* gsrc = (const char*)(y1t + (size_t)n0 * C_);
  char* sbase = (char*)bsm;
#pragma unroll
  for (int r = 0; r < 12; ++r) {
    int L = (r * TPB + tid) * 16;
    int row = L / 384;
    int cb = L - row * 384;
    uint4 v = *(const uint4*)(gsrc + row * 384 + cb);
    *(uint4*)(sbase + (row * 384 + (cb ^ ((row & 7) << 4)))) = v;
  }
  __syncthreads();

  int wid = tid >> 6;
  int lane = tid & 63;
  int col = lane & 15;
  int kg = lane >> 4;

  f32x4 acc[4][2];
#pragma unroll
  for (int mf = 0; mf < 4; ++mf)
#pragma unroll
    for (int nf = 0; nf < 2; ++nf) acc[mf][nf] = (f32x4){0.f, 0.f, 0.f, 0.f};

#pragma unroll
  for (int k0 = 0; k0 < C_; k0 += 32) {
    short8v a[4], bfr[2];
#pragma unroll
    for (int mf = 0; mf < 4; ++mf)
      a[mf] = *(const short8v*)(wtb + (m0 + mf * 16 + col) * C_ + k0 + kg * 8);
#pragma unroll
    for (int nf = 0; nf < 2; ++nf) {
      int brow = wid * 32 + nf * 16 + col;
      int kb = (k0 + kg * 8) * 2;
      bfr[nf] = *(const short8v*)(sbase + brow * 384 + (kb ^ ((brow & 7) << 4)));
    }
#pragma unroll
    for (int mf = 0; mf < 4; ++mf)
#pragma unroll
      for (int nf = 0; nf < 2; ++nf)
        acc[mf][nf] = __builtin_amdgcn_mfma_f32_16x16x32_bf16(a[mf], bfr[nf], acc[mf][nf], 0, 0, 0);
  }

#pragma unroll
  for (int mf = 0; mf < 4; ++mf) {
#pragma unroll
    for (int nf = 0; nf < 2; ++nf) {
      int p = n0 + wid * 32 + nf * 16 + col;
      int bb = p / HW_;
      int hw = p - bb * HW_;
#pragma unroll
      for (int reg = 0; reg < 4; ++reg) {
        int o = m0 + mf * 16 + kg * 4 + reg;
        float a = acc[mf][nf][reg];
        float r = a * fminf(fmaxf(a + 3.f, 0.f), 6.f) * (1.f / 6.f);
        out[((size_t)bb * O_ + o) * HW_ + hw] = r;
      }
    }
  }
}

extern "C" void kernel_launch(void* const* d_in, const int* in_sizes, int n_in,
                              void* d_out, int out_size, void* d_ws, size_t ws_size,
                              hipStream_t stream) {
  const float* x = (const float*)d_in[0];
  const float* og_dw = (const float*)d_in[1];
  const float* og_pw = (const float*)d_in[2];
  const float* dcn_w = (const float*)d_in[3];
  const float* pw_w = (const float*)d_in[4];
  float* out = (float*)d_out;

  float* ws = (float*)d_ws;
  float* t1 = ws;                                        // B*C*HW fp32
  float* offp = t1 + (size_t)B_ * C_ * HW_;              // B*18*HW fp32
  unsigned short* y1t = (unsigned short*)(offp + (size_t)B_ * NOFF * HW_);
  unsigned short* wtb = y1t + (size_t)NPIX * C_;
  unsigned short* x_t = wtb + (size_t)O_ * C_;

  k_wb<<<(O_ * C_ + TPB - 1) / TPB, TPB, 0, stream>>>(pw_w, wtb);
  k_dw<<<(B_ * C_ * HW_ + TPB - 1) / TPB, TPB, 0, stream>>>(x, og_dw, t1);
  k_xt<<<dim3(HW_ / 64, B_), TPB, 0, stream>>>(x, x_t);
  k_pw18<<<(B_ * NOFF * (HW_ / 4)) / TPB, TPB, 0, stream>>>(t1, og_pw, offp);
  k_deform4<<<NPIX / 32, TPB, 0, stream>>>(x_t, offp, dcn_w, y1t);
  k_gemm2<<<dim3(NPIX / 128, O_ / 64), TPB, 0, stream>>>(y1t, wtb, out);
}